// Round 9
// baseline (358.446 us; speedup 1.0000x reference)
//
#include <hip/hip_runtime.h>
#include <hip/hip_fp16.h>

// GAT 2-layer + BN + final linear on MI355X.
// R22: rank || mfma1 overlap + R14 GEMM restored.
//  - R21 post-mortem: R19 register-B GEMM was ~10+us/launch SLOWER than the
//    original LDS-staged GEMM (hidden below the top-5 cutoff both rounds;
//    identified by elimination across R14..R21 totals). Restored verbatim.
//  - rank's 800K atomics are memory-side throughput-bound (~46us, all CU
//    pipes idle) -> overlap them with the layer-1 GEMM instead of fill:
//    k_rank_mfma interleaves roles by blockIdx&1 (782 mfma tiles + 782
//    rank chunks of ~1024 edges). fill (~10us scatter) runs alone after scan.
//  - bnstat grids widened: rowsPerBlock 256->64 (196->782 blocks; bnstat was
//    0.77 blocks/CU).
// Keepers: atomic-rank CSR (best measured), single k_scan w/ atomic block
//  base + degs[], bnfin folded into consumer prologues, attnagg tail skip.

#define NEG_SLOPE 0.2f
#define BN_EPS 1e-5f

typedef short bf16x8 __attribute__((ext_vector_type(8)));
typedef float f32x4 __attribute__((ext_vector_type(4)));

static __device__ __forceinline__ unsigned short f2bf(float f) {
    union { float f; unsigned u; } v; v.f = f;
    unsigned r = v.u + 0x7FFF + ((v.u >> 16) & 1);
    return (unsigned short)(r >> 16);
}
static __device__ __forceinline__ float2 bf2x2(unsigned v) {
    union { unsigned u; float f; } a, b;
    a.u = v << 16; b.u = v & 0xffff0000u;
    return make_float2(a.f, b.f);
}
static __device__ __forceinline__ float halfsel(unsigned p, int head) {
    __half2 h = *(__half2*)&p;
    return head ? __high2float(h) : __low2float(h);
}

// ---------------- BatchNorm stats: vectorized streaming (device fn) ----------------
template <int C>
static __device__ __forceinline__ void d_bnstat(const float* __restrict__ x, int M,
                                                int rowsPerBlock, float* __restrict__ sums,
                                                int b, float* red) {
    constexpr int TPR = C / 4;
    constexpr int RS  = 256 / TPR;
    const int t = threadIdx.x;
    const int cg = t % TPR, rg = t / TPR, w = t >> 6, lane = t & 63;
    int r0 = b * rowsPerBlock + rg;
    int r1 = min(M, b * rowsPerBlock + rowsPerBlock);
    float4 s = make_float4(0, 0, 0, 0), q = make_float4(0, 0, 0, 0);
    #pragma unroll
    for (int r = r0; r < r1; r += RS) {
        float4 v = *(const float4*)&x[(size_t)r * C + cg * 4];
        s.x += v.x; s.y += v.y; s.z += v.z; s.w += v.w;
        q.x += v.x * v.x; q.y += v.y * v.y; q.z += v.z * v.z; q.w += v.w * v.w;
    }
    #pragma unroll
    for (int off = TPR; off < 64; off <<= 1) {
        s.x += __shfl_xor(s.x, off); s.y += __shfl_xor(s.y, off);
        s.z += __shfl_xor(s.z, off); s.w += __shfl_xor(s.w, off);
        q.x += __shfl_xor(q.x, off); q.y += __shfl_xor(q.y, off);
        q.z += __shfl_xor(q.z, off); q.w += __shfl_xor(q.w, off);
    }
    if (lane < TPR) {
        *(float4*)&red[w * 2 * C + cg * 4] = s;
        *(float4*)&red[w * 2 * C + C + cg * 4] = q;
    }
    __syncthreads();
    for (int idx = t; idx < 2 * C; idx += 256) {
        float tot = red[idx] + red[2 * C + idx] + red[4 * C + idx] + red[6 * C + idx];
        atomicAdd(&sums[idx], tot);
    }
}

template <int C>
__global__ __launch_bounds__(256) void k_bnstat2(const float* __restrict__ x, int M,
                                                 int rowsPerBlock, float* __restrict__ sums) {
    __shared__ __align__(16) float red[4 * 2 * C];
    d_bnstat<C>(x, M, rowsPerBlock, sums, blockIdx.x, red);
}

// ---------------- pre: bnstat0 + W^T bf16 ----------------
__global__ __launch_bounds__(256) void k_pre(
    const float* __restrict__ x, int M, int bgrid,
    const float* __restrict__ W1, const float* __restrict__ W2,
    float* __restrict__ sums,
    unsigned short* __restrict__ wt1, unsigned short* __restrict__ wt2) {
    __shared__ __align__(16) float red[4 * 2 * 128];
    int b = blockIdx.x;
    if (b < bgrid) {
        d_bnstat<128>(x, M, 64, sums, b, red);
    } else {
        int idx = (b - bgrid) * 256 + threadIdx.x;
        if (idx < 128 * 128) {
            int n = idx >> 7, k = idx & 127;
            wt1[idx] = f2bf(W1[k * 128 + n]);
            wt2[idx] = f2bf(W2[k * 128 + n]);
        }
    }
}

// ---------------- scan: block prefix + atomic-base segment assignment ----------------
// rowptr is block-scrambled but per-node contiguous; consumers use (rowptr,degs).
__global__ __launch_bounds__(256) void k_scan(const int* __restrict__ cnt, int Nn,
                                              int* __restrict__ gcur,
                                              int* __restrict__ rowptr,
                                              unsigned short* __restrict__ degs) {
    __shared__ int wsum[4];
    __shared__ int s_base;
    int t = threadIdx.x, lane = t & 63, w = t >> 6;
    int i = blockIdx.x * 256 + t;
    int v = (i < Nn) ? cnt[i] + 1 : 0;         // +1: self-loop per node
    int x = v;
    #pragma unroll
    for (int off = 1; off < 64; off <<= 1) {
        int y = __shfl_up(x, off);
        if (lane >= off) x += y;
    }
    if (lane == 63) wsum[w] = x;
    __syncthreads();
    if (t < 4) {
        int val = wsum[t];
        int xs = val;
        #pragma unroll
        for (int off = 1; off < 4; off <<= 1) {
            int y = __shfl_up(xs, off);
            if (t >= off) xs += y;
        }
        if (t == 3) s_base = atomicAdd(gcur, xs);   // block base, any order
        wsum[t] = xs - val;
    }
    __syncthreads();
    if (i < Nn) {
        rowptr[i] = s_base + wsum[w] + (x - v);
        degs[i] = (unsigned short)v;
    }
}

// ---------------- fill: scatter edges into CSR slots ----------------
__global__ __launch_bounds__(256) void k_fill(const int* __restrict__ ei,
                                              const unsigned short* __restrict__ rank,
                                              const int* __restrict__ rowptr, int E, int Nn,
                                              unsigned short* __restrict__ ssrc) {
    int i = blockIdx.x * 256 + threadIdx.x;
    if (i < E) {
        int s = ei[i], d = ei[E + i];
        ssrc[rowptr[d] + 1 + (int)rank[i]] = (unsigned short)s;
    } else if (i < E + Nn) {
        int d = i - E;
        ssrc[rowptr[d]] = (unsigned short)d;   // self-loop slot 0
    }
}

// ---------------- MFMA GEMM [M,128]@[128,128] (R14 LDS-staged version) ----------------
// BN affine computed in prologue from sums; affine(+ELU)+cvt fused in A staging.
static __device__ __forceinline__ void d_mfma(
    int blk, const float* __restrict__ A, const unsigned short* __restrict__ wt,
    const float* __restrict__ sums, const float* __restrict__ bng, const float* __restrict__ bnb,
    int elu, const float* __restrict__ asrc, const float* __restrict__ adst, int M,
    unsigned short* __restrict__ hb, float* __restrict__ als, float* __restrict__ ald) {
    __shared__ unsigned short As[64 * 136];
    __shared__ unsigned short Bs[128 * 136];
    __shared__ __align__(16) float stl[256];
    const int t = threadIdx.x;
    const int w = t >> 6, lane = t & 63;
    const int c = lane & 15, q = lane >> 4;
    const int row0 = blk * 64;

    if (t < 128) {
        float mu = sums[t] / (float)M;
        float var = sums[128 + t] / (float)M - mu * mu;
        float s = bng[t] * rsqrtf(var + BN_EPS);
        stl[t] = s;
        stl[128 + t] = bnb[t] - mu * s;
    }
    __syncthreads();

    #pragma unroll
    for (int i = 0; i < 8; i++) {
        int idx = t + i * 256;
        int r = idx >> 5, ch4 = idx & 31;
        int gr = row0 + r;
        float4 v = make_float4(0, 0, 0, 0);
        if (gr < M) {
            v = *(const float4*)&A[(size_t)gr * 128 + ch4 * 4];
            float4 sc = *(const float4*)&stl[ch4 * 4];
            float4 sh = *(const float4*)&stl[128 + ch4 * 4];
            v.x = v.x * sc.x + sh.x; v.y = v.y * sc.y + sh.y;
            v.z = v.z * sc.z + sh.z; v.w = v.w * sc.w + sh.w;
            if (elu) {
                v.x = v.x > 0.f ? v.x : expm1f(v.x);
                v.y = v.y > 0.f ? v.y : expm1f(v.y);
                v.z = v.z > 0.f ? v.z : expm1f(v.z);
                v.w = v.w > 0.f ? v.w : expm1f(v.w);
            }
        }
        unsigned p0 = ((unsigned)f2bf(v.y) << 16) | f2bf(v.x);
        unsigned p1 = ((unsigned)f2bf(v.w) << 16) | f2bf(v.z);
        *(uint2*)&As[r * 136 + ch4 * 4] = make_uint2(p0, p1);
    }
    #pragma unroll
    for (int i = 0; i < 8; i++) {
        int idx = t + i * 256;
        int r = idx >> 4, ch = idx & 15;
        *(uint4*)&Bs[r * 136 + ch * 8] = *(const uint4*)&wt[(size_t)r * 128 + ch * 8];
    }
    __syncthreads();

    f32x4 acc[8] = {};
    #pragma unroll
    for (int ks = 0; ks < 4; ks++) {
        bf16x8 a = *(bf16x8*)&As[(w * 16 + c) * 136 + (ks * 4 + q) * 8];
        #pragma unroll
        for (int tl = 0; tl < 8; tl++) {
            bf16x8 b = *(bf16x8*)&Bs[(tl * 16 + c) * 136 + (ks * 4 + q) * 8];
            acc[tl] = __builtin_amdgcn_mfma_f32_16x16x32_bf16(a, b, acc[tl], 0, 0, 0);
        }
    }

    #pragma unroll
    for (int reg = 0; reg < 4; reg++) {
        int grow = row0 + w * 16 + q * 4 + reg;
        if (grow < M) {
            #pragma unroll
            for (int tl = 0; tl < 8; tl++)
                hb[(size_t)grow * 128 + tl * 16 + c] = f2bf(acc[tl][reg]);
        }
    }

    float as_[8], ad_[8];
    #pragma unroll
    for (int tl = 0; tl < 8; tl++) { as_[tl] = asrc[tl * 16 + c]; ad_[tl] = adst[tl * 16 + c]; }
    #pragma unroll
    for (int reg = 0; reg < 4; reg++) {
        float s0 = 0.f, s1 = 0.f, d0 = 0.f, d1 = 0.f;
        #pragma unroll
        for (int tl = 0; tl < 4; tl++) { s0 += acc[tl][reg] * as_[tl]; d0 += acc[tl][reg] * ad_[tl]; }
        #pragma unroll
        for (int tl = 4; tl < 8; tl++) { s1 += acc[tl][reg] * as_[tl]; d1 += acc[tl][reg] * ad_[tl]; }
        #pragma unroll
        for (int off = 1; off < 16; off <<= 1) {
            s0 += __shfl_xor(s0, off); s1 += __shfl_xor(s1, off);
            d0 += __shfl_xor(d0, off); d1 += __shfl_xor(d1, off);
        }
        int grow = row0 + w * 16 + q * 4 + reg;
        if (c == 0 && grow < M) {
            *(float2*)&als[(size_t)grow * 2] = make_float2(s0, s1);
            *(float2*)&ald[(size_t)grow * 2] = make_float2(d0, d1);
        }
    }
}

__global__ __launch_bounds__(256) void k_mfma(
    const float* __restrict__ A, const unsigned short* __restrict__ wt,
    const float* __restrict__ sums, const float* __restrict__ bng, const float* __restrict__ bnb,
    int elu, const float* __restrict__ asrc, const float* __restrict__ adst, int M,
    unsigned short* __restrict__ hb, float* __restrict__ als, float* __restrict__ ald) {
    d_mfma(blockIdx.x, A, wt, sums, bng, bnb, elu, asrc, adst, M, hb, als, ald);
}

// ---------------- layer-1 GEMM || rank atomics, interleaved by blockIdx&1 ----------------
// rank is memory-side RMW-throughput-bound with all CU pipes idle -> co-resides
// with the GEMM's load/MFMA work on every CU. Roles alternate so the dispatcher
// gives each CU a mix.
__global__ __launch_bounds__(256) void k_rank_mfma(
    const float* __restrict__ A, const unsigned short* __restrict__ wt,
    const float* __restrict__ sums, const float* __restrict__ bng, const float* __restrict__ bnb,
    const float* __restrict__ asrc, const float* __restrict__ adst, int M, int ggrid,
    unsigned short* __restrict__ hb, float* __restrict__ als, float* __restrict__ ald,
    const int* __restrict__ ei, int E, int rblocks, int chunk,
    int* __restrict__ cnt, unsigned short* __restrict__ rank) {
    int b = blockIdx.x;
    int half = b >> 1;
    if ((b & 1) == 0) {
        if (half < ggrid)
            d_mfma(half, A, wt, sums, bng, bnb, 0, asrc, adst, M, hb, als, ald);
    } else {
        if (half < rblocks) {
            int i1 = min(E, half * chunk + chunk);
            for (int i = half * chunk + threadIdx.x; i < i1; i += 256) {
                int d = ei[E + i];
                rank[i] = (unsigned short)atomicAdd(&cnt[d], 1);
            }
        }
    }
}

// ---------------- fused softmax + aggregation: wave per dst node ----------------
static __device__ __forceinline__ void acc8(float* acc, uint4 v, float a) {
    float2 p;
    p = bf2x2(v.x); acc[0] += a * p.x; acc[1] += a * p.y;
    p = bf2x2(v.y); acc[2] += a * p.x; acc[3] += a * p.y;
    p = bf2x2(v.z); acc[4] += a * p.x; acc[5] += a * p.y;
    p = bf2x2(v.w); acc[6] += a * p.x; acc[7] += a * p.y;
}

template <int MEAN>
static __device__ __forceinline__ void attnagg(
    const int* __restrict__ rowptr, const unsigned short* __restrict__ degs,
    const unsigned short* __restrict__ ssrc,
    const float* __restrict__ als, const float* __restrict__ ald,
    float* __restrict__ alpha, const unsigned short* __restrict__ hb,
    const float* __restrict__ bias, int Nn, float* __restrict__ out) {
    int gw = (blockIdx.x * blockDim.x + threadIdx.x) >> 6;
    if (gw >= Nn) return;
    int lane = threadIdx.x & 63;
    int sub = lane >> 4, c = lane & 15, head = c >> 3;
    int beg = rowptr[gw];
    int deg = (int)degs[gw];
    int end = beg + deg;
    float2 dv = *(const float2*)&ald[(size_t)gw * 2];
    float acc[8] = {};

    if (deg <= 64) {
        bool on = lane < deg;
        int eidx = beg + (on ? lane : 0);
        int sreg = (int)ssrc[eidx];
        float2 av = *(const float2*)&als[(size_t)sreg * 2];
        float v0 = av.x + dv.x; v0 = v0 > 0.f ? v0 : NEG_SLOPE * v0;
        float v1 = av.y + dv.y; v1 = v1 > 0.f ? v1 : NEG_SLOPE * v1;
        // post-BN logits: |v| << 88, exp safe without max-subtraction
        float p0 = on ? __expf(v0) : 0.f;
        float p1 = on ? __expf(v1) : 0.f;
        float t0 = p0, t1 = p1;
        #pragma unroll
        for (int off = 32; off; off >>= 1) {
            t0 += __shfl_xor(t0, off);
            t1 += __shfl_xor(t1, off);
        }
        __half2 hpk = __floats2half2_rn(p0 / t0, p1 / t1);
        unsigned pk = *(unsigned*)&hpk;

        // pass 2: wave-uniform groups of 4 slots; 4-group batches for MLP,
        // then 2-group tail with wave-uniform skip of a fully-inactive 2nd group.
        int nit = (deg + 3) >> 2;
        int it = 0;
        for (; it + 4 <= nit; it += 4) {
            int s_[4]; float a_[4];
            #pragma unroll
            for (int u = 0; u < 4; u++) {
                int jj = (it + u) * 4 + sub;
                int ls = jj & 63;
                s_[u] = __shfl(sreg, ls);
                unsigned pw = (unsigned)__shfl(pk, ls);
                a_[u] = (jj < deg) ? halfsel(pw, head) : 0.f;
            }
            #pragma unroll
            for (int u = 0; u < 4; u++) {
                uint4 v = *(const uint4*)&hb[(size_t)s_[u] * 128 + c * 8];
                acc8(acc, v, a_[u]);
            }
        }
        for (; it < nit; it += 2) {
            const bool two = (it + 1) < nit;    // wave-uniform
            int s_[2]; float a_[2];
            #pragma unroll
            for (int u = 0; u < 2; u++) {
                if (u == 0 || two) {
                    int jj = (it + u) * 4 + sub;
                    int ls = jj & 63;
                    s_[u] = __shfl(sreg, ls);
                    unsigned pw = (unsigned)__shfl(pk, ls);
                    a_[u] = (jj < deg) ? halfsel(pw, head) : 0.f;
                }
            }
            #pragma unroll
            for (int u = 0; u < 2; u++) {
                if (u == 0 || two) {
                    uint4 v = *(const uint4*)&hb[(size_t)s_[u] * 128 + c * 8];
                    acc8(acc, v, a_[u]);
                }
            }
        }
    } else {
        // fallback (deg > 64): alpha via global buffer, with max-subtract
        float d0 = dv.x, d1 = dv.y;
        float m0 = -1e30f, m1 = -1e30f;
        for (int e = beg + lane; e < end; e += 64) {
            int s = (int)ssrc[e];
            float v0 = als[s * 2] + d0;     v0 = v0 > 0.f ? v0 : NEG_SLOPE * v0;
            float v1 = als[s * 2 + 1] + d1; v1 = v1 > 0.f ? v1 : NEG_SLOPE * v1;
            m0 = fmaxf(m0, v0); m1 = fmaxf(m1, v1);
        }
        #pragma unroll
        for (int off = 32; off; off >>= 1) {
            m0 = fmaxf(m0, __shfl_xor(m0, off));
            m1 = fmaxf(m1, __shfl_xor(m1, off));
        }
        float t0 = 0.f, t1 = 0.f;
        for (int e = beg + lane; e < end; e += 64) {
            int s = (int)ssrc[e];
            float v0 = als[s * 2] + d0;     v0 = v0 > 0.f ? v0 : NEG_SLOPE * v0;
            float v1 = als[s * 2 + 1] + d1; v1 = v1 > 0.f ? v1 : NEG_SLOPE * v1;
            float p0 = __expf(v0 - m0), p1 = __expf(v1 - m1);
            alpha[e * 2] = p0; alpha[e * 2 + 1] = p1;
            t0 += p0; t1 += p1;
        }
        #pragma unroll
        for (int off = 32; off; off >>= 1) {
            t0 += __shfl_xor(t0, off);
            t1 += __shfl_xor(t1, off);
        }
        float i0 = 1.f / t0, i1 = 1.f / t1;
        for (int e = beg + sub; e < end; e += 4) {
            int s = (int)ssrc[e];
            float a = (head ? alpha[(size_t)e * 2 + 1] * i1 : alpha[(size_t)e * 2] * i0);
            uint4 v = *(const uint4*)&hb[(size_t)s * 128 + c * 8];
            acc8(acc, v, a);
        }
    }

    #pragma unroll
    for (int j2 = 0; j2 < 8; j2++) {
        acc[j2] += __shfl_xor(acc[j2], 16);
        acc[j2] += __shfl_xor(acc[j2], 32);
        if (MEAN) acc[j2] += __shfl_xor(acc[j2], 8);
    }
    if (MEAN) {
        if (sub == 0 && c < 8) {
            float4 b0 = *(const float4*)&bias[c * 8];
            float4 b1 = *(const float4*)&bias[c * 8 + 4];
            float4 o0 = make_float4(0.5f * acc[0] + b0.x, 0.5f * acc[1] + b0.y, 0.5f * acc[2] + b0.z, 0.5f * acc[3] + b0.w);
            float4 o1 = make_float4(0.5f * acc[4] + b1.x, 0.5f * acc[5] + b1.y, 0.5f * acc[6] + b1.z, 0.5f * acc[7] + b1.w);
            *(float4*)&out[(size_t)gw * 64 + c * 8] = o0;
            *(float4*)&out[(size_t)gw * 64 + c * 8 + 4] = o1;
        }
    } else {
        if (sub == 0) {
            float4 b0 = *(const float4*)&bias[c * 8];
            float4 b1 = *(const float4*)&bias[c * 8 + 4];
            float4 o0 = make_float4(acc[0] + b0.x, acc[1] + b0.y, acc[2] + b0.z, acc[3] + b0.w);
            float4 o1 = make_float4(acc[4] + b1.x, acc[5] + b1.y, acc[6] + b1.z, acc[7] + b1.w);
            *(float4*)&out[(size_t)gw * 128 + c * 8] = o0;
            *(float4*)&out[(size_t)gw * 128 + c * 8 + 4] = o1;
        }
    }
}

__global__ __launch_bounds__(256) void k_attnagg1(const int* __restrict__ rowptr, const unsigned short* __restrict__ degs,
                                                  const unsigned short* __restrict__ ssrc,
                                                  const float* __restrict__ als, const float* __restrict__ ald,
                                                  float* __restrict__ alpha, const unsigned short* __restrict__ hb,
                                                  const float* __restrict__ bias, int Nn, float* __restrict__ out) {
    attnagg<0>(rowptr, degs, ssrc, als, ald, alpha, hb, bias, Nn, out);
}

__global__ __launch_bounds__(256) void k_attnagg2(const int* __restrict__ rowptr, const unsigned short* __restrict__ degs,
                                                  const unsigned short* __restrict__ ssrc,
                                                  const float* __restrict__ als, const float* __restrict__ ald,
                                                  float* __restrict__ alpha, const unsigned short* __restrict__ hb,
                                                  const float* __restrict__ bias, int Nn, float* __restrict__ out) {
    attnagg<1>(rowptr, degs, ssrc, als, ald, alpha, hb, bias, Nn, out);
}

// ---------------- final GEMM [M,64] @ [64,40] + bias, BN affine + ELU fused on A ----------------
__global__ __launch_bounds__(128) void k_gemmf(const float* __restrict__ A, const float* __restrict__ Wf,
                                               const float* __restrict__ bf,
                                               const float* __restrict__ sums, const float* __restrict__ bng,
                                               const float* __restrict__ bnb,
                                               int M, float* __restrict__ out) {
    __shared__ float As[128 * 65];
    __shared__ float Bs[64 * 40];
    __shared__ float stl[128];
    int t = threadIdx.x;
    int row0 = blockIdx.x * 128;
    if (t < 64) {
        float mu = sums[t] / (float)M;
        float var = sums[64 + t] / (float)M - mu * mu;
        float s = bng[t] * rsqrtf(var + BN_EPS);
        stl[t] = s;
        stl[64 + t] = bnb[t] - mu * s;
    }
    __syncthreads();
    for (int i = t; i < 64 * 40; i += 128) Bs[i] = Wf[i];
    for (int i = t; i < 128 * 64; i += 128) {
        int r = i >> 6, k = i & 63;
        int gr = row0 + r;
        float v = 0.f;
        if (gr < M) {
            v = A[(size_t)gr * 64 + k] * stl[k] + stl[64 + k];
            v = v > 0.f ? v : expm1f(v);
        }
        As[r * 65 + k] = v;
    }
    __syncthreads();
    int cg = t & 3, rg = t >> 2;
    float acc[4][10] = {};
    for (int k = 0; k < 64; k++) {
        float b[10];
        #pragma unroll
        for (int j = 0; j < 10; j++) b[j] = Bs[k * 40 + cg * 10 + j];
        #pragma unroll
        for (int r = 0; r < 4; r++) {
            float a = As[(rg * 4 + r) * 65 + k];
            #pragma unroll
            for (int j = 0; j < 10; j++) acc[r][j] += a * b[j];
        }
    }
    for (int r = 0; r < 4; r++) {
        int gr = row0 + rg * 4 + r;
        if (gr < M) {
            #pragma unroll
            for (int j = 0; j < 10; j++) out[(size_t)gr * 40 + cg * 10 + j] = acc[r][j] + bf[cg * 10 + j];
        }
    }
}

extern "C" void kernel_launch(void* const* d_in, const int* in_sizes, int n_in,
                              void* d_out, int out_size, void* d_ws, size_t ws_size,
                              hipStream_t stream) {
    const float* x     = (const float*)d_in[0];
    const int*   ei    = (const int*)d_in[1];
    const float* bn0_g = (const float*)d_in[2];
    const float* bn0_b = (const float*)d_in[3];
    const float* W1    = (const float*)d_in[4];
    const float* a1s   = (const float*)d_in[5];
    const float* a1d   = (const float*)d_in[6];
    const float* b1    = (const float*)d_in[7];
    const float* bn1_g = (const float*)d_in[8];
    const float* bn1_b = (const float*)d_in[9];
    const float* W2    = (const float*)d_in[10];
    const float* a2s   = (const float*)d_in[11];
    const float* a2d   = (const float*)d_in[12];
    const float* b2    = (const float*)d_in[13];
    const float* bn2_g = (const float*)d_in[14];
    const float* bn2_b = (const float*)d_in[15];
    const float* Wf    = (const float*)d_in[16];
    const float* bf    = (const float*)d_in[17];
    float* out = (float*)d_out;

    const int N  = in_sizes[0] / 128;   // 50000 < 65536: u16 ssrc/rank valid
    const int E  = in_sizes[1] / 2;
    const int ET = E + N;

    char* ws = (char*)d_ws;
    size_t off = 0;
    auto alloc = [&](size_t bytes) -> char* {
        char* p = ws + off;
        off = (off + bytes + 255) & ~(size_t)255;
        return p;
    };
    // zero-init region first: sums + gcur + cnt in one memset
    float* sums   = (float*)alloc(644 * 4);           // BN0:0, BN1:+256, BN2:+512, gcur:+640
    int*   gcur   = (int*)(sums + 640);
    int*   cnt    = (int*)alloc((size_t)N * 4);
    const size_t zlen = off;
    int*   rowptr = (int*)alloc((size_t)N * 4);
    unsigned short* degs = (unsigned short*)alloc((size_t)N * 2);
    unsigned short* ssrc = (unsigned short*)alloc((size_t)ET * 2);
    unsigned short* rank = (unsigned short*)alloc((size_t)E * 2);
    float* abuf   = (float*)alloc((size_t)N * 128 * 4);
    unsigned short* hb  = (unsigned short*)alloc((size_t)N * 128 * 2);
    unsigned short* wt1 = (unsigned short*)alloc((size_t)128 * 128 * 2);
    unsigned short* wt2 = (unsigned short*)alloc((size_t)128 * 128 * 2);
    float* alpha  = (float*)alloc((size_t)ET * 2 * 4);   // deg>64 fallback only
    float* als    = (float*)alloc((size_t)N * 2 * 4);
    float* ald    = (float*)alloc((size_t)N * 2 * 4);

    const int tb = 256;
    const int bgrid0 = (N + 63) / 64;         // bnstat grids (rowsPerBlock=64)
    const int sgrid = (N + 255) / 256;        // scan grid
    const int fgrid = (ET + tb - 1) / tb;
    const int wgrid = ((size_t)N * 64 + tb - 1) / tb;
    const int ggrid = (N + 63) / 64;
    const int rblocks = ggrid;                // rank chunks, 1:1 with mfma tiles
    const int chunk = (E + rblocks - 1) / rblocks;

    hipMemsetAsync(ws, 0, zlen, stream);

    // pre: BN0 stats (wide grid) + W^T casts
    k_pre<<<bgrid0 + 64, tb, 0, stream>>>(x, N, bgrid0, W1, W2, sums, wt1, wt2);

    // layer 1 GEMM || rank atomics (interleaved roles)
    k_rank_mfma<<<2 * ggrid, tb, 0, stream>>>(x, wt1, sums, bn0_g, bn0_b,
                                              a1s, a1d, N, ggrid, hb, als, ald,
                                              ei, E, rblocks, chunk, cnt, rank);

    // scan: block prefix + atomic base -> rowptr, degs
    k_scan<<<sgrid, tb, 0, stream>>>(cnt, N, gcur, rowptr, degs);

    // fill CSR
    k_fill<<<fgrid, tb, 0, stream>>>(ei, rank, rowptr, E, N, ssrc);

    k_attnagg1<<<wgrid, tb, 0, stream>>>(rowptr, degs, ssrc, als, ald, alpha, hb, b1, N, abuf);

    // BN1 stats
    k_bnstat2<128><<<bgrid0, 256, 0, stream>>>(abuf, N, 64, sums + 256);

    // layer 2 (BN1 affine from sums in prologue, + ELU)
    k_mfma<<<ggrid, tb, 0, stream>>>(abuf, wt2, sums + 256, bn1_g, bn1_b, 1, a2s, a2d, N, hb, als, ald);
    k_attnagg2<<<wgrid, tb, 0, stream>>>(rowptr, degs, ssrc, als, ald, alpha, hb, b2, N, abuf);

    // BN2 stats
    k_bnstat2<64><<<bgrid0, 256, 0, stream>>>(abuf, N, 64, sums + 512);

    // final linear (BN2 affine from sums in prologue)
    k_gemmf<<<(N + 127) / 128, 128, 0, stream>>>(abuf, Wf, bf, sums + 512, bn2_g, bn2_b, N, out);
}

// Round 10
// 323.015 us; speedup vs baseline: 1.1097x; 1.1097x over previous
//
#include <hip/hip_runtime.h>
#include <hip/hip_fp16.h>

// GAT 2-layer + BN + final linear on MI355X.
// R23: 32-row GEMM blocks.
//  - R22 post-mortem: rank||mfma merge forced 53KB LDS on rank blocks (3
//    blocks/CU for both roles) and wide bnstat 4x'd sums RMW traffic. Both
//    reverted -- launch structure back to R14 (measured 309).
//  - Surviving diagnosis (R17/R18 counters): per-layer GEMM is GRID-capped
//    at 782 blocks = 3/CU = 23-27% occupancy, latency-bound at ~44us vs ~8
//    roofline. Fix the grid: 32-row blocks -> 1563 blocks, ~6/CU.
//  - New d_mfma: 4 waves = (row-half, head) split. Per wave: 16 rows x 64
//    cols, acc[4]. A staged in LDS (8.7KB, no Bs -- B from global wt, L2-hot
//    32KB shared by all blocks). Column split == head boundary, so als/ald
//    need NO cross-wave reduction (wave h writes als[row*2+h] directly).
//    LDS ~10KB -> 8 blocks/CU resident capacity.
// Keepers: k_prep (rank+bnstat0@256+wt), atomic-rank CSR (best measured),
//  k_scan atomic-base + degs, fill||mfma1, bnfin in prologues, attnagg
//  tail skip.

#define NEG_SLOPE 0.2f
#define BN_EPS 1e-5f

typedef short bf16x8 __attribute__((ext_vector_type(8)));
typedef float f32x4 __attribute__((ext_vector_type(4)));

static __device__ __forceinline__ unsigned short f2bf(float f) {
    union { float f; unsigned u; } v; v.f = f;
    unsigned r = v.u + 0x7FFF + ((v.u >> 16) & 1);
    return (unsigned short)(r >> 16);
}
static __device__ __forceinline__ float2 bf2x2(unsigned v) {
    union { unsigned u; float f; } a, b;
    a.u = v << 16; b.u = v & 0xffff0000u;
    return make_float2(a.f, b.f);
}
static __device__ __forceinline__ float halfsel(unsigned p, int head) {
    __half2 h = *(__half2*)&p;
    return head ? __high2float(h) : __low2float(h);
}

// ---------------- BatchNorm stats: vectorized streaming (device fn) ----------------
template <int C>
static __device__ __forceinline__ void d_bnstat(const float* __restrict__ x, int M,
                                                int rowsPerBlock, float* __restrict__ sums,
                                                int b, float* red) {
    constexpr int TPR = C / 4;
    constexpr int RS  = 256 / TPR;
    const int t = threadIdx.x;
    const int cg = t % TPR, rg = t / TPR, w = t >> 6, lane = t & 63;
    int r0 = b * rowsPerBlock + rg;
    int r1 = min(M, b * rowsPerBlock + rowsPerBlock);
    float4 s = make_float4(0, 0, 0, 0), q = make_float4(0, 0, 0, 0);
    #pragma unroll 4
    for (int r = r0; r < r1; r += RS) {
        float4 v = *(const float4*)&x[(size_t)r * C + cg * 4];
        s.x += v.x; s.y += v.y; s.z += v.z; s.w += v.w;
        q.x += v.x * v.x; q.y += v.y * v.y; q.z += v.z * v.z; q.w += v.w * v.w;
    }
    #pragma unroll
    for (int off = TPR; off < 64; off <<= 1) {
        s.x += __shfl_xor(s.x, off); s.y += __shfl_xor(s.y, off);
        s.z += __shfl_xor(s.z, off); s.w += __shfl_xor(s.w, off);
        q.x += __shfl_xor(q.x, off); q.y += __shfl_xor(q.y, off);
        q.z += __shfl_xor(q.z, off); q.w += __shfl_xor(q.w, off);
    }
    if (lane < TPR) {
        *(float4*)&red[w * 2 * C + cg * 4] = s;
        *(float4*)&red[w * 2 * C + C + cg * 4] = q;
    }
    __syncthreads();
    for (int idx = t; idx < 2 * C; idx += 256) {
        float tot = red[idx] + red[2 * C + idx] + red[4 * C + idx] + red[6 * C + idx];
        atomicAdd(&sums[idx], tot);
    }
}

template <int C>
__global__ __launch_bounds__(256) void k_bnstat2(const float* __restrict__ x, int M,
                                                 int rowsPerBlock, float* __restrict__ sums) {
    __shared__ __align__(16) float red[4 * 2 * C];
    d_bnstat<C>(x, M, rowsPerBlock, sums, blockIdx.x, red);
}

// ---------------- prep: rank(atomics) + bnstat0 + W^T bf16 in one dispatch ----------------
__global__ __launch_bounds__(256) void k_prep(
    const int* __restrict__ ei, int E, int rgrid,
    const float* __restrict__ x, int M, int bgrid,
    const float* __restrict__ W1, const float* __restrict__ W2,
    int* __restrict__ cnt, unsigned short* __restrict__ rank,
    float* __restrict__ sums,
    unsigned short* __restrict__ wt1, unsigned short* __restrict__ wt2) {
    __shared__ __align__(16) float red[4 * 2 * 128];
    int b = blockIdx.x;
    if (b < rgrid) {
        int i = b * 256 + threadIdx.x;
        if (i < E) {
            int d = ei[E + i];
            rank[i] = (unsigned short)atomicAdd(&cnt[d], 1);
        }
    } else if (b < rgrid + bgrid) {
        d_bnstat<128>(x, M, 256, sums, b - rgrid, red);
    } else {
        int idx = (b - rgrid - bgrid) * 256 + threadIdx.x;
        if (idx < 128 * 128) {
            int n = idx >> 7, k = idx & 127;
            wt1[idx] = f2bf(W1[k * 128 + n]);
            wt2[idx] = f2bf(W2[k * 128 + n]);
        }
    }
}

// ---------------- scan: block prefix + atomic-base segment assignment ----------------
// rowptr is block-scrambled but per-node contiguous; consumers use (rowptr,degs).
__global__ __launch_bounds__(256) void k_scan(const int* __restrict__ cnt, int Nn,
                                              int* __restrict__ gcur,
                                              int* __restrict__ rowptr,
                                              unsigned short* __restrict__ degs) {
    __shared__ int wsum[4];
    __shared__ int s_base;
    int t = threadIdx.x, lane = t & 63, w = t >> 6;
    int i = blockIdx.x * 256 + t;
    int v = (i < Nn) ? cnt[i] + 1 : 0;         // +1: self-loop per node
    int x = v;
    #pragma unroll
    for (int off = 1; off < 64; off <<= 1) {
        int y = __shfl_up(x, off);
        if (lane >= off) x += y;
    }
    if (lane == 63) wsum[w] = x;
    __syncthreads();
    if (t < 4) {
        int val = wsum[t];
        int xs = val;
        #pragma unroll
        for (int off = 1; off < 4; off <<= 1) {
            int y = __shfl_up(xs, off);
            if (t >= off) xs += y;
        }
        if (t == 3) s_base = atomicAdd(gcur, xs);   // block base, any order
        wsum[t] = xs - val;
    }
    __syncthreads();
    if (i < Nn) {
        rowptr[i] = s_base + wsum[w] + (x - v);
        degs[i] = (unsigned short)v;
    }
}

// ---------------- fill (device fn, merged with layer-1 mfma) ----------------
static __device__ __forceinline__ void d_fill(int b, const int* __restrict__ ei,
                                              const unsigned short* __restrict__ rank,
                                              const int* __restrict__ rowptr, int E, int Nn,
                                              unsigned short* __restrict__ ssrc) {
    int i = b * 256 + threadIdx.x;
    if (i < E) {
        int s = ei[i], d = ei[E + i];
        ssrc[rowptr[d] + 1 + (int)rank[i]] = (unsigned short)s;
    } else if (i < E + Nn) {
        int d = i - E;
        ssrc[rowptr[d]] = (unsigned short)d;   // self-loop slot 0
    }
}

// ---------------- MFMA GEMM [M,128]@[128,128], 32-row blocks ----------------
// 4 waves = (row-half rw, head h). Per wave: 16 rows x 64 cols, acc[4].
// A staged in LDS (8.7KB); B direct from global wt (L2-hot). Column split
// aligns with head boundary: wave h writes als/ald[row*2+h] directly.
static __device__ __forceinline__ void d_mfma(
    int blk, const float* __restrict__ A, const unsigned short* __restrict__ wt,
    const float* __restrict__ sums, const float* __restrict__ bng, const float* __restrict__ bnb,
    int elu, const float* __restrict__ asrc, const float* __restrict__ adst, int M,
    unsigned short* __restrict__ hb, float* __restrict__ als, float* __restrict__ ald) {
    __shared__ unsigned short As[32 * 136];
    __shared__ __align__(16) float stl[256];
    const int t = threadIdx.x;
    const int w = t >> 6, lane = t & 63;
    const int c = lane & 15, q = lane >> 4;
    const int rw = w & 1, h = w >> 1;
    const int row0 = blk * 32;

    if (t < 128) {
        float mu = sums[t] / (float)M;
        float var = sums[128 + t] / (float)M - mu * mu;
        float s = bng[t] * rsqrtf(var + BN_EPS);
        stl[t] = s;
        stl[128 + t] = bnb[t] - mu * s;
    }
    __syncthreads();

    // A staging: 32 rows x 128 cols, BN affine (+ELU) + bf16 pack fused
    #pragma unroll
    for (int i = 0; i < 4; i++) {
        int idx = t + i * 256;
        int r = idx >> 5, ch4 = idx & 31;
        int gr = row0 + r;
        float4 v = make_float4(0, 0, 0, 0);
        if (gr < M) {
            v = *(const float4*)&A[(size_t)gr * 128 + ch4 * 4];
            float4 sc = *(const float4*)&stl[ch4 * 4];
            float4 sh = *(const float4*)&stl[128 + ch4 * 4];
            v.x = v.x * sc.x + sh.x; v.y = v.y * sc.y + sh.y;
            v.z = v.z * sc.z + sh.z; v.w = v.w * sc.w + sh.w;
            if (elu) {
                v.x = v.x > 0.f ? v.x : expm1f(v.x);
                v.y = v.y > 0.f ? v.y : expm1f(v.y);
                v.z = v.z > 0.f ? v.z : expm1f(v.z);
                v.w = v.w > 0.f ? v.w : expm1f(v.w);
            }
        }
        unsigned p0 = ((unsigned)f2bf(v.y) << 16) | f2bf(v.x);
        unsigned p1 = ((unsigned)f2bf(v.w) << 16) | f2bf(v.z);
        *(uint2*)&As[r * 136 + ch4 * 4] = make_uint2(p0, p1);
    }
    __syncthreads();

    f32x4 acc[4] = {};
    #pragma unroll
    for (int ks = 0; ks < 4; ks++) {
        bf16x8 a = *(bf16x8*)&As[(rw * 16 + c) * 136 + (ks * 4 + q) * 8];
        #pragma unroll
        for (int tl = 0; tl < 4; tl++) {
            bf16x8 b = *(const bf16x8*)&wt[(size_t)((h * 4 + tl) * 16 + c) * 128 + (ks * 4 + q) * 8];
            acc[tl] = __builtin_amdgcn_mfma_f32_16x16x32_bf16(a, b, acc[tl], 0, 0, 0);
        }
    }

    // hb write: wave covers rows rw*16.. cols h*64..h*64+63
    #pragma unroll
    for (int reg = 0; reg < 4; reg++) {
        int grow = row0 + rw * 16 + q * 4 + reg;
        if (grow < M) {
            #pragma unroll
            for (int tl = 0; tl < 4; tl++)
                hb[(size_t)grow * 128 + h * 64 + tl * 16 + c] = f2bf(acc[tl][reg]);
        }
    }

    // als/ald: full head-h dot per row (no cross-wave reduction needed)
    float as_[4], ad_[4];
    #pragma unroll
    for (int tl = 0; tl < 4; tl++) {
        as_[tl] = asrc[h * 64 + tl * 16 + c];
        ad_[tl] = adst[h * 64 + tl * 16 + c];
    }
    #pragma unroll
    for (int reg = 0; reg < 4; reg++) {
        float s = 0.f, d = 0.f;
        #pragma unroll
        for (int tl = 0; tl < 4; tl++) { s += acc[tl][reg] * as_[tl]; d += acc[tl][reg] * ad_[tl]; }
        #pragma unroll
        for (int off = 1; off < 16; off <<= 1) {
            s += __shfl_xor(s, off); d += __shfl_xor(d, off);
        }
        int grow = row0 + rw * 16 + q * 4 + reg;
        if (c == 0 && grow < M) {
            als[(size_t)grow * 2 + h] = s;
            ald[(size_t)grow * 2 + h] = d;
        }
    }
}

__global__ __launch_bounds__(256) void k_mfma(
    const float* __restrict__ A, const unsigned short* __restrict__ wt,
    const float* __restrict__ sums, const float* __restrict__ bng, const float* __restrict__ bnb,
    int elu, const float* __restrict__ asrc, const float* __restrict__ adst, int M,
    unsigned short* __restrict__ hb, float* __restrict__ als, float* __restrict__ ald) {
    d_mfma(blockIdx.x, A, wt, sums, bng, bnb, elu, asrc, adst, M, hb, als, ald);
}

// layer-1 GEMM + CSR fill co-executing in one dispatch (independent after scan)
__global__ __launch_bounds__(256) void k_fill_mfma(
    const float* __restrict__ A, const unsigned short* __restrict__ wt,
    const float* __restrict__ sums, const float* __restrict__ bng, const float* __restrict__ bnb,
    const float* __restrict__ asrc, const float* __restrict__ adst, int M, int ggrid,
    unsigned short* __restrict__ hb, float* __restrict__ als, float* __restrict__ ald,
    const int* __restrict__ ei, const unsigned short* __restrict__ rank,
    const int* __restrict__ rowptr, int E, int Nn, unsigned short* __restrict__ ssrc) {
    if (blockIdx.x < ggrid)
        d_mfma(blockIdx.x, A, wt, sums, bng, bnb, 0, asrc, adst, M, hb, als, ald);
    else
        d_fill(blockIdx.x - ggrid, ei, rank, rowptr, E, Nn, ssrc);
}

// ---------------- fused softmax + aggregation: wave per dst node ----------------
static __device__ __forceinline__ void acc8(float* acc, uint4 v, float a) {
    float2 p;
    p = bf2x2(v.x); acc[0] += a * p.x; acc[1] += a * p.y;
    p = bf2x2(v.y); acc[2] += a * p.x; acc[3] += a * p.y;
    p = bf2x2(v.z); acc[4] += a * p.x; acc[5] += a * p.y;
    p = bf2x2(v.w); acc[6] += a * p.x; acc[7] += a * p.y;
}

template <int MEAN>
static __device__ __forceinline__ void attnagg(
    const int* __restrict__ rowptr, const unsigned short* __restrict__ degs,
    const unsigned short* __restrict__ ssrc,
    const float* __restrict__ als, const float* __restrict__ ald,
    float* __restrict__ alpha, const unsigned short* __restrict__ hb,
    const float* __restrict__ bias, int Nn, float* __restrict__ out) {
    int gw = (blockIdx.x * blockDim.x + threadIdx.x) >> 6;
    if (gw >= Nn) return;
    int lane = threadIdx.x & 63;
    int sub = lane >> 4, c = lane & 15, head = c >> 3;
    int beg = rowptr[gw];
    int deg = (int)degs[gw];
    int end = beg + deg;
    float2 dv = *(const float2*)&ald[(size_t)gw * 2];
    float acc[8] = {};

    if (deg <= 64) {
        bool on = lane < deg;
        int eidx = beg + (on ? lane : 0);
        int sreg = (int)ssrc[eidx];
        float2 av = *(const float2*)&als[(size_t)sreg * 2];
        float v0 = av.x + dv.x; v0 = v0 > 0.f ? v0 : NEG_SLOPE * v0;
        float v1 = av.y + dv.y; v1 = v1 > 0.f ? v1 : NEG_SLOPE * v1;
        // post-BN logits: |v| << 88, exp safe without max-subtraction
        float p0 = on ? __expf(v0) : 0.f;
        float p1 = on ? __expf(v1) : 0.f;
        float t0 = p0, t1 = p1;
        #pragma unroll
        for (int off = 32; off; off >>= 1) {
            t0 += __shfl_xor(t0, off);
            t1 += __shfl_xor(t1, off);
        }
        __half2 hpk = __floats2half2_rn(p0 / t0, p1 / t1);
        unsigned pk = *(unsigned*)&hpk;

        // pass 2: wave-uniform groups of 4 slots; 4-group batches for MLP,
        // then 2-group tail with wave-uniform skip of a fully-inactive 2nd group.
        int nit = (deg + 3) >> 2;
        int it = 0;
        for (; it + 4 <= nit; it += 4) {
            int s_[4]; float a_[4];
            #pragma unroll
            for (int u = 0; u < 4; u++) {
                int jj = (it + u) * 4 + sub;
                int ls = jj & 63;
                s_[u] = __shfl(sreg, ls);
                unsigned pw = (unsigned)__shfl(pk, ls);
                a_[u] = (jj < deg) ? halfsel(pw, head) : 0.f;
            }
            #pragma unroll
            for (int u = 0; u < 4; u++) {
                uint4 v = *(const uint4*)&hb[(size_t)s_[u] * 128 + c * 8];
                acc8(acc, v, a_[u]);
            }
        }
        for (; it < nit; it += 2) {
            const bool two = (it + 1) < nit;    // wave-uniform
            int s_[2]; float a_[2];
            #pragma unroll
            for (int u = 0; u < 2; u++) {
                if (u == 0 || two) {
                    int jj = (it + u) * 4 + sub;
                    int ls = jj & 63;
                    s_[u] = __shfl(sreg, ls);
                    unsigned pw = (unsigned)__shfl(pk, ls);
                    a_[u] = (jj < deg) ? halfsel(pw, head) : 0.f;
                }
            }
            #pragma unroll
            for (int u = 0; u < 2; u++) {
                if (u == 0 || two) {
                    uint4 v = *(const uint4*)&hb[(size_t)s_[u] * 128 + c * 8];
                    acc8(acc, v, a_[u]);
                }
            }
        }
    } else {
        // fallback (deg > 64): alpha via global buffer, with max-subtract
        float d0 = dv.x, d1 = dv.y;
        float m0 = -1e30f, m1 = -1e30f;
        for (int e = beg + lane; e < end; e += 64) {
            int s = (int)ssrc[e];
            float v0 = als[s * 2] + d0;     v0 = v0 > 0.f ? v0 : NEG_SLOPE * v0;
            float v1 = als[s * 2 + 1] + d1; v1 = v1 > 0.f ? v1 : NEG_SLOPE * v1;
            m0 = fmaxf(m0, v0); m1 = fmaxf(m1, v1);
        }
        #pragma unroll
        for (int off = 32; off; off >>= 1) {
            m0 = fmaxf(m0, __shfl_xor(m0, off));
            m1 = fmaxf(m1, __shfl_xor(m1, off));
        }
        float t0 = 0.f, t1 = 0.f;
        for (int e = beg + lane; e < end; e += 64) {
            int s = (int)ssrc[e];
            float v0 = als[s * 2] + d0;     v0 = v0 > 0.f ? v0 : NEG_SLOPE * v0;
            float v1 = als[s * 2 + 1] + d1; v1 = v1 > 0.f ? v1 : NEG_SLOPE * v1;
            float p0 = __expf(v0 - m0), p1 = __expf(v1 - m1);
            alpha[e * 2] = p0; alpha[e * 2 + 1] = p1;
            t0 += p0; t1 += p1;
        }
        #pragma unroll
        for (int off = 32; off; off >>= 1) {
            t0 += __shfl_xor(t0, off);
            t1 += __shfl_xor(t1, off);
        }
        float i0 = 1.f / t0, i1 = 1.f / t1;
        for (int e = beg + sub; e < end; e += 4) {
            int s = (int)ssrc[e];
            float a = (head ? alpha[(size_t)e * 2 + 1] * i1 : alpha[(size_t)e * 2] * i0);
            uint4 v = *(const uint4*)&hb[(size_t)s * 128 + c * 8];
            acc8(acc, v, a);
        }
    }

    #pragma unroll
    for (int j2 = 0; j2 < 8; j2++) {
        acc[j2] += __shfl_xor(acc[j2], 16);
        acc[j2] += __shfl_xor(acc[j2], 32);
        if (MEAN) acc[j2] += __shfl_xor(acc[j2], 8);
    }
    if (MEAN) {
        if (sub == 0 && c < 8) {
            float4 b0 = *(const float4*)&bias[c * 8];
            float4 b1 = *(const float4*)&bias[c * 8 + 4];
            float4 o0 = make_float4(0.5f * acc[0] + b0.x, 0.5f * acc[1] + b0.y, 0.5f * acc[2] + b0.z, 0.5f * acc[3] + b0.w);
            float4 o1 = make_float4(0.5f * acc[4] + b1.x, 0.5f * acc[5] + b1.y, 0.5f * acc[6] + b1.z, 0.5f * acc[7] + b1.w);
            *(float4*)&out[(size_t)gw * 64 + c * 8] = o0;
            *(float4*)&out[(size_t)gw * 64 + c * 8 + 4] = o1;
        }
    } else {
        if (sub == 0) {
            float4 b0 = *(const float4*)&bias[c * 8];
            float4 b1 = *(const float4*)&bias[c * 8 + 4];
            float4 o0 = make_float4(acc[0] + b0.x, acc[1] + b0.y, acc[2] + b0.z, acc[3] + b0.w);
            float4 o1 = make_float4(acc[4] + b1.x, acc[5] + b1.y, acc[6] + b1.z, acc[7] + b1.w);
            *(float4*)&out[(size_t)gw * 128 + c * 8] = o0;
            *(float4*)&out[(size_t)gw * 128 + c * 8 + 4] = o1;
        }
    }
}

__global__ __launch_bounds__(256) void k_attnagg1(const int* __restrict__ rowptr, const unsigned short* __restrict__ degs,
                                                  const unsigned short* __restrict__ ssrc,
                                                  const float* __restrict__ als, const float* __restrict__ ald,
                                                  float* __restrict__ alpha, const unsigned short* __restrict__ hb,
                                                  const float* __restrict__ bias, int Nn, float* __restrict__ out) {
    attnagg<0>(rowptr, degs, ssrc, als, ald, alpha, hb, bias, Nn, out);
}

__global__ __launch_bounds__(256) void k_attnagg2(const int* __restrict__ rowptr, const unsigned short* __restrict__ degs,
                                                  const unsigned short* __restrict__ ssrc,
                                                  const float* __restrict__ als, const float* __restrict__ ald,
                                                  float* __restrict__ alpha, const unsigned short* __restrict__ hb,
                                                  const float* __restrict__ bias, int Nn, float* __restrict__ out) {
    attnagg<1>(rowptr, degs, ssrc, als, ald, alpha, hb, bias, Nn, out);
}

// ---------------- final GEMM [M,64] @ [64,40] + bias, BN affine + ELU fused on A ----------------
__global__ __launch_bounds__(128) void k_gemmf(const float* __restrict__ A, const float* __restrict__ Wf,
                                               const float* __restrict__ bf,
                                               const float* __restrict__ sums, const float* __restrict__ bng,
                                               const float* __restrict__ bnb,
                                               int M, float* __restrict__ out) {
    __shared__ float As[128 * 65];
    __shared__ float Bs[64 * 40];
    __shared__ float stl[128];
    int t = threadIdx.x;
    int row0 = blockIdx.x * 128;
    if (t < 64) {
        float mu = sums[t] / (float)M;
        float var = sums[64 + t] / (float)M - mu * mu;
        float s = bng[t] * rsqrtf(var + BN_EPS);
        stl[t] = s;
        stl[64 + t] = bnb[t] - mu * s;
    }
    __syncthreads();
    for (int i = t; i < 64 * 40; i += 128) Bs[i] = Wf[i];
    for (int i = t; i < 128 * 64; i += 128) {
        int r = i >> 6, k = i & 63;
        int gr = row0 + r;
        float v = 0.f;
        if (gr < M) {
            v = A[(size_t)gr * 64 + k] * stl[k] + stl[64 + k];
            v = v > 0.f ? v : expm1f(v);
        }
        As[r * 65 + k] = v;
    }
    __syncthreads();
    int cg = t & 3, rg = t >> 2;
    float acc[4][10] = {};
    for (int k = 0; k < 64; k++) {
        float b[10];
        #pragma unroll
        for (int j = 0; j < 10; j++) b[j] = Bs[k * 40 + cg * 10 + j];
        #pragma unroll
        for (int r = 0; r < 4; r++) {
            float a = As[(rg * 4 + r) * 65 + k];
            #pragma unroll
            for (int j = 0; j < 10; j++) acc[r][j] += a * b[j];
        }
    }
    for (int r = 0; r < 4; r++) {
        int gr = row0 + rg * 4 + r;
        if (gr < M) {
            #pragma unroll
            for (int j = 0; j < 10; j++) out[(size_t)gr * 40 + cg * 10 + j] = acc[r][j] + bf[cg * 10 + j];
        }
    }
}

extern "C" void kernel_launch(void* const* d_in, const int* in_sizes, int n_in,
                              void* d_out, int out_size, void* d_ws, size_t ws_size,
                              hipStream_t stream) {
    const float* x     = (const float*)d_in[0];
    const int*   ei    = (const int*)d_in[1];
    const float* bn0_g = (const float*)d_in[2];
    const float* bn0_b = (const float*)d_in[3];
    const float* W1    = (const float*)d_in[4];
    const float* a1s   = (const float*)d_in[5];
    const float* a1d   = (const float*)d_in[6];
    const float* b1    = (const float*)d_in[7];
    const float* bn1_g = (const float*)d_in[8];
    const float* bn1_b = (const float*)d_in[9];
    const float* W2    = (const float*)d_in[10];
    const float* a2s   = (const float*)d_in[11];
    const float* a2d   = (const float*)d_in[12];
    const float* b2    = (const float*)d_in[13];
    const float* bn2_g = (const float*)d_in[14];
    const float* bn2_b = (const float*)d_in[15];
    const float* Wf    = (const float*)d_in[16];
    const float* bf    = (const float*)d_in[17];
    float* out = (float*)d_out;

    const int N  = in_sizes[0] / 128;   // 50000 < 65536: u16 ssrc/rank valid
    const int E  = in_sizes[1] / 2;
    const int ET = E + N;

    char* ws = (char*)d_ws;
    size_t off = 0;
    auto alloc = [&](size_t bytes) -> char* {
        char* p = ws + off;
        off = (off + bytes + 255) & ~(size_t)255;
        return p;
    };
    // zero-init region first: sums + gcur + cnt in one memset
    float* sums   = (float*)alloc(644 * 4);           // BN0:0, BN1:+256, BN2:+512, gcur:+640
    int*   gcur   = (int*)(sums + 640);
    int*   cnt    = (int*)alloc((size_t)N * 4);
    const size_t zlen = off;
    int*   rowptr = (int*)alloc((size_t)N * 4);
    unsigned short* degs = (unsigned short*)alloc((size_t)N * 2);
    unsigned short* ssrc = (unsigned short*)alloc((size_t)ET * 2);
    unsigned short* rank = (unsigned short*)alloc((size_t)E * 2);
    float* abuf   = (float*)alloc((size_t)N * 128 * 4);
    unsigned short* hb  = (unsigned short*)alloc((size_t)N * 128 * 2);
    unsigned short* wt1 = (unsigned short*)alloc((size_t)128 * 128 * 2);
    unsigned short* wt2 = (unsigned short*)alloc((size_t)128 * 128 * 2);
    float* alpha  = (float*)alloc((size_t)ET * 2 * 4);   // deg>64 fallback only
    float* als    = (float*)alloc((size_t)N * 2 * 4);
    float* ald    = (float*)alloc((size_t)N * 2 * 4);

    const int tb = 256;
    const int rgrid = (E + tb - 1) / tb;
    const int bgrid = (N + 255) / 256;        // bnstat grids (rowsPerBlock=256)
    const int fgrid = (ET + tb - 1) / tb;
    const int wgrid = ((size_t)N * 64 + tb - 1) / tb;
    const int ggrid = (N + 31) / 32;          // 32-row GEMM blocks

    hipMemsetAsync(ws, 0, zlen, stream);

    // prep: rank atomics + BN0 stats + W^T casts co-execute
    k_prep<<<rgrid + bgrid + 64, tb, 0, stream>>>(ei, E, rgrid, x, N, bgrid, W1, W2,
                                                  cnt, rank, sums, wt1, wt2);
    // scan: block prefix + atomic base -> rowptr, degs
    k_scan<<<bgrid, tb, 0, stream>>>(cnt, N, gcur, rowptr, degs);

    // layer 1 GEMM (BN0 affine from sums in prologue) + CSR fill co-execute
    k_fill_mfma<<<ggrid + fgrid, tb, 0, stream>>>(x, wt1, sums, bn0_g, bn0_b,
                                                  a1s, a1d, N, ggrid, hb, als, ald,
                                                  ei, rank, rowptr, E, N, ssrc);
    k_attnagg1<<<wgrid, tb, 0, stream>>>(rowptr, degs, ssrc, als, ald, alpha, hb, b1, N, abuf);

    // BN1 stats
    k_bnstat2<128><<<bgrid, 256, 0, stream>>>(abuf, N, 256, sums + 256);

    // layer 2 (BN1 affine from sums in prologue, + ELU)
    k_mfma<<<ggrid, tb, 0, stream>>>(abuf, wt2, sums + 256, bn1_g, bn1_b, 1, a2s, a2d, N, hb, als, ald);
    k_attnagg2<<<wgrid, tb, 0, stream>>>(rowptr, degs, ssrc, als, ald, alpha, hb, b2, N, abuf);

    // BN2 stats
    k_bnstat2<64><<<bgrid, 256, 0, stream>>>(abuf, N, 256, sums + 512);

    // final linear (BN2 affine from sums in prologue)
    k_gemmf<<<(N + 127) / 128, 128, 0, stream>>>(abuf, Wf, bf, sums + 512, bn2_g, bn2_b, N, out);
}